// Round 10
// baseline (512.724 us; speedup 1.0000x reference)
//
#include <hip/hip_runtime.h>
#include <hip/hip_fp16.h>

#define NEG_SLOPE 0.2f
#define BKN 128                 // nodes per bucket (pow2)
#define MAXNB 1024              // supports n <= 131072
#define GRP 256                 // pass1/ghist groups (blocks), private cursors

typedef _Float16 half_t;
typedef __attribute__((ext_vector_type(8))) _Float16 half8;
typedef __attribute__((ext_vector_type(4))) float floatx4;

// ---------------------------------------------------------------------------
// Weight transpose + fp16 convert for BOTH layers in one launch.
// ---------------------------------------------------------------------------
__global__ __launch_bounds__(256) void w_convert2(
    const float* __restrict__ W1, half_t* __restrict__ Wt1,
    const float* __restrict__ W2, half_t* __restrict__ Wt2)
{
    int i = blockIdx.x * 256 + threadIdx.x;
    if (i < 128 * 128) {
        int k = i / 128, nn = i % 128;
        Wt1[nn * 128 + k] = (half_t)W1[i];
    } else if (i < 128 * 128 + 128 * 64) {
        int j = i - 128 * 128;
        int k = j / 64, nn = j % 64;
        Wt2[nn * 128 + k] = (half_t)W2[j];
    }
}

// ---------------------------------------------------------------------------
// MFMA GEMM + fused attention logits (mfma 16x16x32 f16, fp32 acc).
// H is stored GROUP-MAJOR: H[g][node][32 feats] (g = 32-col group), so the
// aggregation passes gather one 64B line per edge from a 6.4MB slice.
// ---------------------------------------------------------------------------
template<int BN, int HEADS>
__global__ __launch_bounds__(256) void gemm_mfma(
    const float* __restrict__ X, const half_t* __restrict__ Wt,
    const float* __restrict__ atts, const float* __restrict__ attd,
    half_t* __restrict__ H, float* __restrict__ As, float* __restrict__ Ad,
    int n)
{
    constexpr int K  = 128;
    constexpr int NT = BN / 16;           // col tiles
    constexpr int TPH = NT / HEADS;       // col tiles per head

    __shared__ half_t Wl[BN * K];
    __shared__ half_t Xl[64 * K];

    const int t = threadIdx.x;
    const int wave = t >> 6, lane = t & 63;
    const int quad = lane >> 4, c = lane & 15;

    float att_s[NT], att_d[NT];
    #pragma unroll
    for (int nt = 0; nt < NT; ++nt) {
        att_s[nt] = atts[nt * 16 + c];
        att_d[nt] = attd[nt * 16 + c];
    }

    for (int i = t; i < BN * 16; i += 256) {
        int row = i >> 4, cid = i & 15;
        half8 v = *(const half8*)(Wt + row * K + cid * 8);
        *(half8*)(Wl + row * K + ((cid ^ (row & 15)) << 3)) = v;
    }

    const int numTiles = (n + 63) / 64;
    for (int tile = blockIdx.x; tile < numTiles; tile += gridDim.x) {
        const int row0 = tile * 64;
        __syncthreads();
        for (int i = t; i < 1024; i += 256) {
            int m = i >> 4, cid = i & 15;
            int row = row0 + m;
            float4 a = make_float4(0.f,0.f,0.f,0.f), b = a;
            if (row < n) {
                const float4* src = (const float4*)(X + (size_t)row * K + cid * 8);
                a = src[0]; b = src[1];
            }
            half8 h;
            h[0]=(half_t)a.x; h[1]=(half_t)a.y; h[2]=(half_t)a.z; h[3]=(half_t)a.w;
            h[4]=(half_t)b.x; h[5]=(half_t)b.y; h[6]=(half_t)b.z; h[7]=(half_t)b.w;
            *(half8*)(Xl + m * K + ((cid ^ (m & 15)) << 3)) = h;
        }
        __syncthreads();

        floatx4 acc[NT];
        #pragma unroll
        for (int i = 0; i < NT; ++i) acc[i] = (floatx4)(0.f);

        #pragma unroll
        for (int kc = 0; kc < 4; ++kc) {
            int cid = kc * 4 + quad;
            half8 afrag = *(const half8*)(Xl + (wave * 16 + c) * K + ((cid ^ c) << 3));
            #pragma unroll
            for (int nt = 0; nt < NT; ++nt) {
                half8 bfrag = *(const half8*)(Wl + (nt * 16 + c) * K + ((cid ^ c) << 3));
                acc[nt] = __builtin_amdgcn_mfma_f32_16x16x32_f16(afrag, bfrag, acc[nt], 0, 0, 0);
            }
        }

        #pragma unroll
        for (int reg = 0; reg < 4; ++reg) {
            int row = row0 + wave * 16 + quad * 4 + reg;
            bool ok = row < n;
            if (ok) {
                #pragma unroll
                for (int nt = 0; nt < NT; ++nt) {
                    int g  = nt >> 1;                   // 32-col group
                    int cf = ((nt & 1) << 4) + c;       // col within group
                    H[((size_t)g * n + row) * 32 + cf] = (half_t)acc[nt][reg];
                }
            }
            #pragma unroll
            for (int h = 0; h < HEADS; ++h) {
                float ps = 0.f, pd = 0.f;
                #pragma unroll
                for (int u = 0; u < TPH; ++u) {
                    int nt = h * TPH + u;
                    ps += acc[nt][reg] * att_s[nt];
                    pd += acc[nt][reg] * att_d[nt];
                }
                #pragma unroll
                for (int off = 1; off < 16; off <<= 1) {
                    ps += __shfl_xor(ps, off);
                    pd += __shfl_xor(pd, off);
                }
                if (ok && c == 0) {
                    As[(size_t)row * HEADS + h] = ps;
                    Ad[(size_t)row * HEADS + h] = pd;
                }
            }
        }
    }
}

// ---------------------------------------------------------------------------
// CSR build (contention-free bucketed counting sort, per-group cursors).
// ---------------------------------------------------------------------------
__global__ __launch_bounds__(256) void ghist(
    const int* __restrict__ ei, int E, int Etot, int NB, int chunk,
    int* __restrict__ cnt)
{
    __shared__ int h[MAXNB];
    int g = blockIdx.x;
    for (int i = threadIdx.x; i < NB; i += 256) h[i] = 0;
    __syncthreads();
    int lo = g * chunk, hi = min(Etot, lo + chunk);
    for (int e = lo + threadIdx.x; e < hi; e += 256) {
        int dst = (e < E) ? ei[E + e] : (e - E);
        atomicAdd(&h[dst >> 7], 1);
    }
    __syncthreads();
    for (int i = threadIdx.x; i < NB; i += 256) cnt[i * GRP + g] = h[i];
}

__global__ __launch_bounds__(256) void scan_blocks(
    int* __restrict__ data, int n, int* __restrict__ bsum)
{
    __shared__ int s[256];
    int t = threadIdx.x;
    int idx = blockIdx.x * 1024 + t * 4;
    int4 v = make_int4(0, 0, 0, 0);
    if (idx + 3 < n)      v = *(const int4*)(data + idx);
    else {
        if (idx     < n) v.x = data[idx];
        if (idx + 1 < n) v.y = data[idx+1];
        if (idx + 2 < n) v.z = data[idx+2];
        if (idx + 3 < n) v.w = data[idx+3];
    }
    int tsum = v.x + v.y + v.z + v.w;
    s[t] = tsum;
    __syncthreads();
    for (int off = 1; off < 256; off <<= 1) {
        int x = (t >= off) ? s[t - off] : 0;
        __syncthreads();
        s[t] += x;
        __syncthreads();
    }
    int excl = s[t] - tsum;
    if (t == 255) bsum[blockIdx.x] = s[255];
    if (idx     < n) data[idx]     = excl;
    if (idx + 1 < n) data[idx + 1] = excl + v.x;
    if (idx + 2 < n) data[idx + 2] = excl + v.x + v.y;
    if (idx + 3 < n) data[idx + 3] = excl + v.x + v.y + v.z;
}

__global__ __launch_bounds__(256) void scan_sums(int* __restrict__ bsum, int nb)
{
    __shared__ int s[256];
    int t = threadIdx.x;
    int v = (t < nb) ? bsum[t] : 0;
    s[t] = v;
    __syncthreads();
    for (int off = 1; off < 256; off <<= 1) {
        int x = (t >= off) ? s[t - off] : 0;
        __syncthreads();
        s[t] += x;
        __syncthreads();
    }
    if (t < nb) bsum[t] = s[t] - v;
}

__global__ __launch_bounds__(256) void scan_add(
    int* __restrict__ data, int n, const int* __restrict__ bsum)
{
    int i = blockIdx.x * 256 + threadIdx.x;
    if (i < n) data[i] += bsum[i >> 10];
}

__global__ __launch_bounds__(256) void pass1_scatter(
    const int* __restrict__ ei, int E, int Etot, int NB, int chunk,
    const int* __restrict__ S, unsigned* __restrict__ tmp)
{
    __shared__ int cur[MAXNB];
    int g = blockIdx.x;
    for (int i = threadIdx.x; i < NB; i += 256) cur[i] = S[i * GRP + g];
    __syncthreads();
    int lo = g * chunk, hi = min(Etot, lo + chunk);
    for (int e = lo + threadIdx.x; e < hi; e += 256) {
        int src, dst;
        if (e < E) { src = ei[e]; dst = ei[E + e]; }
        else       { src = dst = e - E; }
        int pos = atomicAdd(&cur[dst >> 7], 1);   // LDS atomic, private row
        tmp[pos] = ((unsigned)src << 7) | (unsigned)(dst & (BKN - 1));
    }
}

__global__ __launch_bounds__(256) void pass2_sort(
    const unsigned* __restrict__ tmp, const int* __restrict__ S,
    int NB, int Etot,
    int* __restrict__ offs, int* __restrict__ esrc, int n)
{
    __shared__ int cnt[BKN];
    __shared__ int sc[BKN];
    __shared__ int cur[BKN];
    int bk = blockIdx.x;
    int t  = threadIdx.x;
    if (t < BKN) cnt[t] = 0;
    __syncthreads();
    int lo = S[bk * GRP];
    int hi = (bk + 1 < NB) ? S[(bk + 1) * GRP] : Etot;
    for (int i = lo + t; i < hi; i += 256)
        atomicAdd(&cnt[tmp[i] & (BKN - 1)], 1);
    __syncthreads();
    int v = (t < BKN) ? cnt[t] : 0;
    if (t < BKN) sc[t] = v;
    __syncthreads();
    for (int off = 1; off < BKN; off <<= 1) {
        int x = (t < BKN && t >= off) ? sc[t - off] : 0;
        __syncthreads();
        if (t < BKN) sc[t] += x;
        __syncthreads();
    }
    if (t < BKN) {
        int node = bk * BKN + t;
        if (node < n) offs[node] = lo + sc[t];   // inclusive scan -> end(v)
        cur[t] = lo + sc[t] - v;                 // exclusive -> begin cursor
    }
    __syncthreads();
    for (int i = lo + t; i < hi; i += 256) {
        unsigned w = tmp[i];
        int p = atomicAdd(&cur[w & (BKN - 1)], 1);
        esrc[p] = (int)(w >> 7);
    }
}

// ---------------------------------------------------------------------------
// Aggregation pass over ONE 32-feature group: one wave per dst node,
// QUARTER-WAVE per edge (16 lanes x half2 = 64B = one line per edge).
// Hg points at this group's [n][32] fp16 slice (6.4MB working set -> L2).
// hh = attention head for this group (group g for layer1, 0 for layer2).
// Fuses normalize + bias (+ ELU for layer1). Out row stride ldout, cols
// [colbase, colbase+32).
// ---------------------------------------------------------------------------
template<int HEADS, bool ELU>
__global__ __launch_bounds__(256) void agg_pass(
    const int* __restrict__ offs, const int* __restrict__ esrc,
    const __half2* __restrict__ Hg, const float* __restrict__ As,
    const float* __restrict__ Ad, const float* __restrict__ bias32,
    float* __restrict__ Out, int n, int hh, int ldout, int colbase)
{
    int v    = (blockIdx.x * 256 + threadIdx.x) >> 6;
    int lane = threadIdx.x & 63;
    if (v >= n) return;
    int q  = lane >> 4;
    int li = lane & 15;
    int end = offs[v];
    int beg = v ? offs[v - 1] : 0;
    float adv = Ad[(size_t)v * HEADS + hh];
    float ax = 0.f, ay = 0.f, den = 0.f;
    int j = beg + q;
    for (; j + 7 < end; j += 8) {          // edges j and j+4 for this quarter
        int s0 = esrc[j], s1 = esrc[j + 4];
        float e0 = As[(size_t)s0 * HEADS + hh] + adv;
        float e1 = As[(size_t)s1 * HEADS + hh] + adv;
        __half2 q0 = Hg[(size_t)s0 * 16 + li];
        __half2 q1 = Hg[(size_t)s1 * 16 + li];
        e0 = e0 > 0.f ? e0 : NEG_SLOPE * e0;  float w0 = __expf(e0);
        e1 = e1 > 0.f ? e1 : NEG_SLOPE * e1;  float w1 = __expf(e1);
        float2 f0 = __half22float2(q0);
        float2 f1 = __half22float2(q1);
        ax += w0 * f0.x + w1 * f1.x;
        ay += w0 * f0.y + w1 * f1.y;
        den += w0 + w1;
    }
    for (; j < end; j += 4) {
        int s = esrc[j];
        float e = As[(size_t)s * HEADS + hh] + adv;
        e = e > 0.f ? e : NEG_SLOPE * e;
        float w = __expf(e);
        float2 f = __half22float2(Hg[(size_t)s * 16 + li]);
        ax += w * f.x; ay += w * f.y; den += w;
    }
    #pragma unroll
    for (int off = 16; off <= 32; off <<= 1) {
        ax += __shfl_xor(ax, off);
        ay += __shfl_xor(ay, off);
        den += __shfl_xor(den, off);
    }
    if (lane < 16) {
        float inv = 1.f / (den + 1e-16f);
        float2 b = ((const float2*)bias32)[li];
        float ox = ax * inv + b.x, oy = ay * inv + b.y;
        if (ELU) {
            ox = ox > 0.f ? ox : __expf(ox) - 1.f;
            oy = oy > 0.f ? oy : __expf(oy) - 1.f;
        }
        ((float2*)(Out + (size_t)v * ldout + colbase))[li] = make_float2(ox, oy);
    }
}

extern "C" void kernel_launch(void* const* d_in, const int* in_sizes, int n_in,
                              void* d_out, int out_size, void* d_ws, size_t ws_size,
                              hipStream_t stream)
{
    (void)n_in; (void)out_size; (void)ws_size;
    const float* x   = (const float*)d_in[0];
    const int*   ei  = (const int*)  d_in[1];
    const float* W1  = (const float*)d_in[2];
    const float* as1 = (const float*)d_in[3];
    const float* ad1 = (const float*)d_in[4];
    const float* b1  = (const float*)d_in[5];
    const float* W2  = (const float*)d_in[6];
    const float* as2 = (const float*)d_in[7];
    const float* ad2 = (const float*)d_in[8];
    const float* b2  = (const float*)d_in[9];
    float* out = (float*)d_out;

    const int n    = in_sizes[0] / 128;   // 100000
    const int E    = in_sizes[1] / 2;     // 1600000
    const int Etot = E + n;               // + self loops
    const int NB   = (n + BKN - 1) / BKN; // buckets (782)
    const int chunk = (Etot + GRP - 1) / GRP;

    // Workspace layout (bytes). Layer-2 buffers overlay consumed layer-1 ones.
    char* p = (char*)d_ws;
    half_t* Hh = (half_t*)p;  p += (size_t)n * 128 * sizeof(half_t);  // 25.6MB
    float* X2  = (float*)p;   p += (size_t)n * 128 * sizeof(float);   // 51.2MB
    float* As1 = (float*)p;   p += (size_t)n * 4 * sizeof(float);     // (L2: As2=n)
    float* Ad1 = (float*)p;   p += (size_t)n * 4 * sizeof(float);     // (L2: Ad2=n)
    int* offs  = (int*)p;     p += (size_t)n * sizeof(int);
    int* esrc  = (int*)p;     p += (size_t)Etot * sizeof(int);
    unsigned* tmp = (unsigned*)p; p += (size_t)Etot * sizeof(unsigned);
    int* cnt   = (int*)p;     p += (size_t)NB * GRP * sizeof(int);    // 0.8MB
    int* bsum  = (int*)p;     p += 1024;
    half_t* Wt1 = (half_t*)p; p += 128 * 128 * sizeof(half_t);        // 32KB
    half_t* Wt2 = (half_t*)p; p += 64 * 128 * sizeof(half_t);         // 16KB

    const int scan_n  = NB * GRP;
    const int scan_nb = (scan_n + 1023) / 1024;   // <=256

    // ---- weight convert (both layers, one launch) ----
    w_convert2<<<(128 * 192 + 255) / 256, 256, 0, stream>>>(W1, Wt1, W2, Wt2);

    // ---- CSR build (contention-free bucketed counting sort) ----
    ghist<<<GRP, 256, 0, stream>>>(ei, E, Etot, NB, chunk, cnt);
    scan_blocks<<<scan_nb, 256, 0, stream>>>(cnt, scan_n, bsum);
    scan_sums<<<1, 256, 0, stream>>>(bsum, scan_nb);
    scan_add<<<(scan_n + 255) / 256, 256, 0, stream>>>(cnt, scan_n, bsum);
    pass1_scatter<<<GRP, 256, 0, stream>>>(ei, E, Etot, NB, chunk, cnt, tmp);
    pass2_sort<<<NB, 256, 0, stream>>>(tmp, cnt, NB, Etot, offs, esrc, n);

    const int gtiles = (n + 63) / 64;
    const int ablocks = (n * 64 + 255) / 256;

    // ---- Layer 1 ----
    gemm_mfma<128, 4><<<gtiles, 256, 0, stream>>>(x, Wt1, as1, ad1, Hh, As1, Ad1, n);
    for (int g = 0; g < 4; ++g)
        agg_pass<4, true><<<ablocks, 256, 0, stream>>>(
            offs, esrc, (const __half2*)(Hh + (size_t)g * n * 32),
            As1, Ad1, b1 + g * 32, X2, n, g, 128, g * 32);

    // ---- Layer 2 ----
    gemm_mfma<64, 1><<<gtiles, 256, 0, stream>>>(X2, Wt2, as2, ad2, Hh, As1, Ad1, n);
    for (int g = 0; g < 2; ++g)
        agg_pass<1, false><<<ablocks, 256, 0, stream>>>(
            offs, esrc, (const __half2*)(Hh + (size_t)g * n * 32),
            As1, Ad1, b2 + g * 32, out, n, 0, 64, g * 32);
}